// Round 3
// baseline (3442.101 us; speedup 1.0000x reference)
//
#include <hip/hip_runtime.h>

// Problem constants (B=4, N=2048, C=256, H=8, D=32, keep = int(2048*0.3) = 614)
#define BDIM 4
#define NSEQ 2048
#define CDIM 256
#define NHEADS 8
#define QB 8                     // query rows per block (2 per wave)
#define NKEEP 614                // int(2048 * (1.0 - 0.7))
#define ATTN_SCALE 0.17677669529663688f  // 32^-0.5

// -------------------------------------------------------------------------
// GEMM: C[M][Nt] = A[M][K] @ W[Nt][K]^T + bias[Nt]   (unchanged, validated)
// -------------------------------------------------------------------------
__global__ __launch_bounds__(256) void gemm_nt_bias(
    const float* __restrict__ A, const float* __restrict__ W,
    const float* __restrict__ bias, float* __restrict__ C,
    int M, int Nt, int K)
{
    __shared__ __align__(16) float As[32][68];
    __shared__ __align__(16) float Ws[32][68];
    const int tid = threadIdx.x;
    const int bm = blockIdx.x * 64;
    const int bn = blockIdx.y * 64;
    const int tm = tid >> 4;
    const int tn = tid & 15;
    const int lr = tid >> 2;
    const int lq = tid & 3;
    const float* Ap = A + (size_t)(bm + lr) * K + lq * 8;
    const float* Wp = W + (size_t)(bn + lr) * K + lq * 8;
    float acc[4][4] = {};

    for (int k0 = 0; k0 < K; k0 += 32) {
        float4 a0 = *(const float4*)(Ap + k0);
        float4 a1 = *(const float4*)(Ap + k0 + 4);
        float4 w0 = *(const float4*)(Wp + k0);
        float4 w1 = *(const float4*)(Wp + k0 + 4);
        __syncthreads();
        const int kq = lq * 8;
        As[kq+0][lr]=a0.x; As[kq+1][lr]=a0.y; As[kq+2][lr]=a0.z; As[kq+3][lr]=a0.w;
        As[kq+4][lr]=a1.x; As[kq+5][lr]=a1.y; As[kq+6][lr]=a1.z; As[kq+7][lr]=a1.w;
        Ws[kq+0][lr]=w0.x; Ws[kq+1][lr]=w0.y; Ws[kq+2][lr]=w0.z; Ws[kq+3][lr]=w0.w;
        Ws[kq+4][lr]=w1.x; Ws[kq+5][lr]=w1.y; Ws[kq+6][lr]=w1.z; Ws[kq+7][lr]=w1.w;
        __syncthreads();
        #pragma unroll
        for (int k = 0; k < 32; ++k) {
            float4 av = *(const float4*)&As[k][tm*4];
            float4 wv = *(const float4*)&Ws[k][tn*4];
            acc[0][0] += av.x*wv.x; acc[0][1] += av.x*wv.y; acc[0][2] += av.x*wv.z; acc[0][3] += av.x*wv.w;
            acc[1][0] += av.y*wv.x; acc[1][1] += av.y*wv.y; acc[1][2] += av.y*wv.z; acc[1][3] += av.y*wv.w;
            acc[2][0] += av.z*wv.x; acc[2][1] += av.z*wv.y; acc[2][2] += av.z*wv.z; acc[2][3] += av.z*wv.w;
            acc[3][0] += av.w*wv.x; acc[3][1] += av.w*wv.y; acc[3][2] += av.w*wv.z; acc[3][3] += av.w*wv.w;
        }
    }
    float4 bb = *(const float4*)(bias + bn + tn*4);
    #pragma unroll
    for (int i = 0; i < 4; ++i) {
        float4 o;
        o.x = acc[i][0] + bb.x;
        o.y = acc[i][1] + bb.y;
        o.z = acc[i][2] + bb.z;
        o.w = acc[i][3] + bb.w;
        *(float4*)(C + (size_t)(bm + tm*4 + i) * Nt + bn + tn*4) = o;
    }
}

// -------------------------------------------------------------------------
// Fused sparse attention, register-resident scores.
// Wave w owns query rows 2w, 2w+1. Thread (w, l) owns columns j = 64*t + l.
// K/V staged 64 rows x 32 floats per tile, triple-buffered, global_load_lds
// with pre-swizzled source so ds_read_b128 is bank-conflict-free.
// Ring discipline per iteration: vmcnt(tile t landed) -> barrier -> stage(t+2)
// -> compute(t). The barrier precedes the overwrite of buf[(t-1)%3], so no
// wave can clobber a tile another wave is still reading.
// -------------------------------------------------------------------------
__device__ __forceinline__ unsigned int f2key(float f) {
    unsigned int u = __float_as_uint(f);
    return (u & 0x80000000u) ? ~u : (u | 0x80000000u);  // monotone order-preserving
}

typedef __attribute__((address_space(1))) const void gas_void;
typedef __attribute__((address_space(3))) void las_void;

__device__ __forceinline__ void gload_lds16(const float* g, float4* l) {
    __builtin_amdgcn_global_load_lds((gas_void*)g, (las_void*)l, 16, 0, 0);
}

// stage 64 rows x 32 floats (global row stride 768 floats) into dst4[512]
// LDS layout: float4 slot = row*8 + (cc ^ (row&7))  (xor swizzle via source;
// LDS side stays lane-linear as global_load_lds requires)
__device__ __forceinline__ void stage64(const float* __restrict__ g, float4* dst4, int tid) {
    const int s0 = tid, s1 = tid + 256;
    const int r0 = s0 >> 3, c0 = (s0 & 7) ^ (r0 & 7);
    const int r1 = s1 >> 3, c1 = (s1 & 7) ^ (r1 & 7);
    gload_lds16(g + (size_t)r0 * 768 + c0 * 4, dst4 + s0);
    gload_lds16(g + (size_t)r1 * 768 + c1 * 4, dst4 + s1);
}

// raw barrier: drain LDS ops, do NOT drain vmcnt (keeps prefetch in flight)
#define RBAR() do { asm volatile("s_waitcnt lgkmcnt(0)" ::: "memory"); \
                    __builtin_amdgcn_s_barrier();                      \
                    asm volatile("" ::: "memory"); } while (0)

__global__ __launch_bounds__(256) void sparse_attn(
    const float* __restrict__ qkv, float* __restrict__ aout)
{
    __shared__ __align__(16) float4 kbuf[3][512];   // 24 KB tile ring (K then V)
    __shared__ unsigned int hist[QB * 256];          // 8 KB
    __shared__ unsigned int prefS[QB];
    __shared__ int remS[QB];
    __shared__ float thrS[QB];

    const int tid  = threadIdx.x;
    const int l    = tid & 63;        // lane in wave
    const int w    = tid >> 6;        // wave id 0..3
    const int li   = l & 31;
    const int half = l >> 5;          // 0 -> row 2w, 1 -> row 2w+1
    const int myrow = 2 * w + half;
    const int swz  = l & 7;

    const int blk = blockIdx.x;
    const int nb  = NSEQ / QB;        // 256 q-blocks per (b,h)
    const int bh  = blk / nb;
    const int qb  = blk % nb;
    const int b   = bh / NHEADS;
    const int h   = bh % NHEADS;
    const int n0  = qb * QB;

    const float* base = qkv + (size_t)b * NSEQ * 768;
    const float* gq = base + (size_t)n0 * 768 + h * 32;
    const float* gk = base + 256 + h * 32;
    const float* gv = base + 512 + h * 32;

    // --- Q for rows 2w, 2w+1 into registers (broadcast loads, L1-served) ---
    float4 q0[8], q1[8];
    {
        const float4* q0p = (const float4*)(gq + (size_t)(2 * w) * 768);
        const float4* q1p = (const float4*)(gq + (size_t)(2 * w + 1) * 768);
        #pragma unroll
        for (int c = 0; c < 8; ++c) { q0[c] = q0p[c]; q1[c] = q1p[c]; }
    }
    if (tid < QB) { prefS[tid] = 0u; remS[tid] = NKEEP; }

    float sA[32], sB[32];

    // ---- Phase B: scores (K tiles, triple-buffered, counted vmcnt) ----
    stage64(gk, &kbuf[0][0], tid);
    stage64(gk + (size_t)64 * 768, &kbuf[1][0], tid);
    #pragma unroll
    for (int t = 0; t < 32; ++t) {
        // wait: tile t landed (tiles t+1[, t+2 not yet issued] may stay in flight)
        if (t + 1 < 32) asm volatile("s_waitcnt vmcnt(2)" ::: "memory");
        else            asm volatile("s_waitcnt vmcnt(0)" ::: "memory");
        RBAR();   // all waves done with tile t-1 reads; safe to overwrite its buffer
        if (t + 2 < 32) stage64(gk + (size_t)(t + 2) * 64 * 768, &kbuf[(t + 2) % 3][0], tid);
        const float4* kb = &kbuf[t % 3][0];
        float a0e = 0.f, a0o = 0.f, a1e = 0.f, a1o = 0.f;
        #pragma unroll
        for (int cc = 0; cc < 8; ++cc) {
            float4 kv = kb[l * 8 + (cc ^ swz)];
            a0e = fmaf(q0[cc].x, kv.x, a0e); a0o = fmaf(q0[cc].y, kv.y, a0o);
            a0e = fmaf(q0[cc].z, kv.z, a0e); a0o = fmaf(q0[cc].w, kv.w, a0o);
            a1e = fmaf(q1[cc].x, kv.x, a1e); a1o = fmaf(q1[cc].y, kv.y, a1o);
            a1e = fmaf(q1[cc].z, kv.z, a1e); a1o = fmaf(q1[cc].w, kv.w, a1o);
        }
        sA[t] = (a0e + a0o) * ATTN_SCALE;
        sB[t] = (a1e + a1o) * ATTN_SCALE;
    }

    // All waves done reading K tiles after this barrier -> start V tiles 0,1;
    // they fly across the whole select/softmax phase (RBAR never drains vmcnt).
    RBAR();
    stage64(gv, &kbuf[0][0], tid);
    stage64(gv + (size_t)64 * 768, &kbuf[1][0], tid);

    // ---- Phase C: exact 614th-largest per row, radix select on f2key ----
    #pragma unroll
    for (int pass = 3; pass >= 0; --pass) {
        #pragma unroll
        for (int i = 0; i < 8; ++i) hist[tid + 256 * i] = 0u;
        RBAR();
        const int sh = pass * 8;
        const unsigned int hmsk = (pass == 3) ? 0u : (0xFFFFFFFFu << (sh + 8));
        const unsigned int pr0 = prefS[2 * w];
        const unsigned int pr1 = prefS[2 * w + 1];
        #pragma unroll
        for (int t = 0; t < 32; ++t) {
            unsigned int k0 = f2key(sA[t]);
            if ((k0 & hmsk) == pr0) atomicAdd(&hist[(2 * w) * 256 + ((k0 >> sh) & 255u)], 1u);
            unsigned int k1 = f2key(sB[t]);
            if ((k1 & hmsk) == pr1) atomicAdd(&hist[(2 * w + 1) * 256 + ((k1 >> sh) & 255u)], 1u);
        }
        RBAR();
        // suffix scan: half-wave (32 lanes) per row, lane li owns bins [8li, 8li+8)
        unsigned int cnt[8];
        unsigned int part = 0u;
        #pragma unroll
        for (int i = 0; i < 8; ++i) { cnt[i] = hist[myrow * 256 + li * 8 + i]; part += cnt[i]; }
        unsigned int suf = part;
        #pragma unroll
        for (int dlt = 1; dlt < 32; dlt <<= 1) {
            unsigned int v = __shfl_down(suf, dlt, 32);
            if (li + dlt < 32) suf += v;
        }
        unsigned int run = suf - part;     // elems in bins owned by lanes > li
        const int remv = remS[myrow];
        const unsigned int prm = half ? pr1 : pr0;
        #pragma unroll
        for (int i = 7; i >= 0; --i) {
            if ((int)run < remv && remv <= (int)(run + cnt[i])) {
                remS[myrow]  = remv - (int)run;
                prefS[myrow] = prm | ((unsigned int)(li * 8 + i) << sh);
            }
            run += cnt[i];
        }
        RBAR();
    }
    if (tid < QB) {
        unsigned int key = prefS[tid];
        unsigned int u = (key & 0x80000000u) ? (key & 0x7FFFFFFFu) : ~key;
        thrS[tid] = __uint_as_float(u);
    }
    RBAR();

    // ---- Phase D: masked softmax on register scores ----
    const float thr0 = thrS[2 * w], thr1 = thrS[2 * w + 1];
    float m0 = 0.f, m1 = 0.f;   // >=1434 masked zeros always present
    #pragma unroll
    for (int t = 0; t < 32; ++t) {
        sA[t] = (sA[t] >= thr0) ? sA[t] : 0.f;
        sB[t] = (sB[t] >= thr1) ? sB[t] : 0.f;
        m0 = fmaxf(m0, sA[t]); m1 = fmaxf(m1, sB[t]);
    }
    #pragma unroll
    for (int d2 = 32; d2 >= 1; d2 >>= 1) {
        m0 = fmaxf(m0, __shfl_xor(m0, d2));
        m1 = fmaxf(m1, __shfl_xor(m1, d2));
    }
    float Z0 = 0.f, Z1 = 0.f;
    #pragma unroll
    for (int t = 0; t < 32; ++t) {
        float p0 = __expf(sA[t] - m0); sA[t] = p0; Z0 += p0;
        float p1 = __expf(sB[t] - m1); sB[t] = p1; Z1 += p1;
    }
    #pragma unroll
    for (int d2 = 32; d2 >= 1; d2 >>= 1) { Z0 += __shfl_xor(Z0, d2); Z1 += __shfl_xor(Z1, d2); }

    // ---- Phase E: PV (V tiles, same ring; tiles 0,1 already in flight) ----
    float oA[32], oB[32];
    #pragma unroll
    for (int d = 0; d < 32; ++d) { oA[d] = 0.f; oB[d] = 0.f; }
    #pragma unroll
    for (int t = 0; t < 32; ++t) {
        if (t + 1 < 32) asm volatile("s_waitcnt vmcnt(2)" ::: "memory");
        else            asm volatile("s_waitcnt vmcnt(0)" ::: "memory");
        RBAR();   // all waves done with V tile t-1 reads; safe to overwrite
        if (t + 2 < 32) stage64(gv + (size_t)(t + 2) * 64 * 768, &kbuf[(t + 2) % 3][0], tid);
        const float4* vb = &kbuf[t % 3][0];
        const float pa = sA[t], pb = sB[t];
        #pragma unroll
        for (int cc = 0; cc < 8; ++cc) {
            float4 vv = vb[l * 8 + (cc ^ swz)];
            oA[4*cc+0] = fmaf(pa, vv.x, oA[4*cc+0]); oA[4*cc+1] = fmaf(pa, vv.y, oA[4*cc+1]);
            oA[4*cc+2] = fmaf(pa, vv.z, oA[4*cc+2]); oA[4*cc+3] = fmaf(pa, vv.w, oA[4*cc+3]);
            oB[4*cc+0] = fmaf(pb, vv.x, oB[4*cc+0]); oB[4*cc+1] = fmaf(pb, vv.y, oB[4*cc+1]);
            oB[4*cc+2] = fmaf(pb, vv.z, oB[4*cc+2]); oB[4*cc+3] = fmaf(pb, vv.w, oB[4*cc+3]);
        }
    }

    // ---- cross-lane reduce: fold rows to halves, then width-32 butterfly ----
    float oC[32];
    #pragma unroll
    for (int d = 0; d < 32; ++d) {
        float ta = oA[d] + __shfl_xor(oA[d], 32);
        float tb = oB[d] + __shfl_xor(oB[d], 32);
        oC[d] = half ? tb : ta;
    }
    #pragma unroll
    for (int d2 = 16; d2 >= 1; d2 >>= 1) {
        #pragma unroll
        for (int d = 0; d < 32; ++d) oC[d] += __shfl_xor(oC[d], d2);
    }
    // lane (half, li) writes out[row=2w+half][d=li]; static-index extraction
    float val = 0.f;
    #pragma unroll
    for (int dd = 0; dd < 32; ++dd) if (li == dd) val = oC[dd];
    val /= (half ? Z1 : Z0);
    aout[((size_t)b * NSEQ + n0 + myrow) * CDIM + h * 32 + li] = val;
}

// -------------------------------------------------------------------------
extern "C" void kernel_launch(void* const* d_in, const int* in_sizes, int n_in,
                              void* d_out, int out_size, void* d_ws, size_t ws_size,
                              hipStream_t stream) {
    (void)in_sizes; (void)n_in; (void)out_size; (void)ws_size;
    const float* x      = (const float*)d_in[0];
    const float* w_qkv  = (const float*)d_in[1];
    const float* b_qkv  = (const float*)d_in[2];
    const float* w_proj = (const float*)d_in[3];
    const float* b_proj = (const float*)d_in[4];
    float* out = (float*)d_out;

    const int M = BDIM * NSEQ;  // 8192
    float* qkv_ws  = (float*)d_ws;                       // 25.2 MB
    float* attn_ws = qkv_ws + (size_t)M * 768;           // 8.4 MB

    // 1) QKV GEMM -> [B][N][3][H][D]
    dim3 g1(M / 64, 768 / 64);
    gemm_nt_bias<<<g1, 256, 0, stream>>>(x, w_qkv, b_qkv, qkv_ws, M, 768, 256);

    // 2) fused sparse attention -> [B][N][C]
    sparse_attn<<<BDIM * NHEADS * NSEQ / QB, 256, 0, stream>>>(qkv_ws, attn_ws);

    // 3) projection GEMM -> d_out
    dim3 g2(M / 64, 256 / 64);
    gemm_nt_bias<<<g2, 256, 0, stream>>>(attn_ws, w_proj, b_proj, out, M, 256, 256);
}